// Round 1
// baseline (345.111 us; speedup 1.0000x reference)
//
#include <hip/hip_runtime.h>

typedef __bf16 bf16_t;
typedef __attribute__((ext_vector_type(8))) __bf16 bf16x8;
typedef __attribute__((ext_vector_type(4))) float f32x4;

#define IMG_H 56
#define IMG_W 56
#define CIN 256
#define COUT 256
#define TH 8      // output rows per block
#define TW 16     // output cols per block (padded to 64 across W)
#define XR 10     // input halo rows
#define XCOL 18   // input halo cols
#define CK 32     // c-chunk per stage
#define CPAD 40   // padded c dim in LDS (80B stride -> 2-way banks, 16B aligned)

// ---------------- weight transform: W[k][c][3][3] fp32 -> wt[t][k][c] bf16 ----
__global__ void wt_transform(const float* __restrict__ W, bf16_t* __restrict__ wt) {
    int o = blockIdx.x * 256 + threadIdx.x;
    if (o >= 9 * COUT * CIN) return;
    int c = o & 255;
    int k = (o >> 8) & 255;
    int t = o >> 16;
    wt[o] = (bf16_t)W[(k * CIN + c) * 9 + t];
}

// ---------------- main conv: implicit GEMM, bf16 MFMA ------------------------
__global__ __launch_bounds__(256, 2)
void conv_mfma(const float* __restrict__ x, const bf16_t* __restrict__ wt,
               float* __restrict__ out) {
    __shared__ bf16_t xs[XR * XCOL * CPAD];   // 14400 B
    __shared__ bf16_t bs[COUT * CPAD];        // 20480 B

    const int tid  = threadIdx.x;
    const int lane = tid & 63;
    const int wid  = tid >> 6;
    const int n    = blockIdx.z;
    const int h0   = blockIdx.y * TH;
    const int w0   = blockIdx.x * TW;

    const int wm  = wid >> 1;       // wave m-half (0..1): rows wm*4 .. wm*4+7 of pixel tile
    const int n0w = (wid & 1) * 128;

    const int pc = lane & 15;       // A-row / B-col within fragment
    const int g  = lane >> 4;       // 0..3
    const int c0 = g * 8;           // reduction sub-slice

    f32x4 acc[4][8] = {};           // 64 pixels x 128 channels per wave

    for (int cc = 0; cc < CIN; cc += CK) {
        for (int t = 0; t < 9; ++t) {
            __syncthreads();        // prior compute done before overwriting LDS
            if (t == 0) {
                // stage x halo tile for this c-chunk: xs[r][col][ci]
                for (int e = tid; e < XR * XCOL * CK; e += 256) {
                    int col = e % XCOL;
                    int r   = (e / XCOL) % XR;
                    int ci  = e / (XCOL * XR);
                    int hh = h0 - 1 + r;
                    int ww = w0 - 1 + col;
                    float v = 0.f;
                    if ((unsigned)hh < (unsigned)IMG_H && (unsigned)ww < (unsigned)IMG_W)
                        v = x[((n * CIN + cc + ci) * IMG_H + hh) * IMG_W + ww];
                    xs[(r * XCOL + col) * CPAD + ci] = (bf16_t)v;
                }
            }
            {
                // stage B tile: bs[k][ci] = wt[t][k][cc+ci]; thread tid <-> k
                const bf16_t* src = wt + ((t * COUT + tid) * CIN + cc);
                #pragma unroll
                for (int i = 0; i < CK / 8; ++i) {
                    bf16x8 v = *(const bf16x8*)(src + i * 8);
                    *(bf16x8*)(&bs[tid * CPAD + i * 8]) = v;
                }
            }
            __syncthreads();

            const int dh = t / 3, dw = t - 3 * dh;
            bf16x8 a[4], b[8];
            #pragma unroll
            for (int fm = 0; fm < 4; ++fm) {
                int pr = wm * 4 + fm;
                a[fm] = *(const bf16x8*)&xs[((pr + dh) * XCOL + (pc + dw)) * CPAD + c0];
            }
            #pragma unroll
            for (int fn = 0; fn < 8; ++fn) {
                int k = n0w + fn * 16 + pc;
                b[fn] = *(const bf16x8*)&bs[k * CPAD + c0];
            }
            #pragma unroll
            for (int fm = 0; fm < 4; ++fm) {
                #pragma unroll
                for (int fn = 0; fn < 8; ++fn) {
                    acc[fm][fn] = __builtin_amdgcn_mfma_f32_16x16x32_bf16(
                        a[fm], b[fn], acc[fm][fn], 0, 0, 0);
                }
            }
        }
    }

    // epilogue: C/D layout col=lane&15 (k), row=(lane>>4)*4+reg (pixel)
    const int pc4  = g * 4;
    const int wcol = w0 + pc4;
    if (wcol < IMG_W) {
        #pragma unroll
        for (int fm = 0; fm < 4; ++fm) {
            int hh = h0 + wm * 4 + fm;
            #pragma unroll
            for (int fn = 0; fn < 8; ++fn) {
                int k = n0w + fn * 16 + pc;
                *(f32x4*)&out[((n * COUT + k) * IMG_H + hh) * IMG_W + wcol] = acc[fm][fn];
            }
        }
    }
}

// ---------------- fallback (only if d_ws is too small): naive fp32 conv ------
__global__ void conv_naive(const float* __restrict__ x, const float* __restrict__ W,
                           float* __restrict__ out, int total) {
    int i = blockIdx.x * 256 + threadIdx.x;
    if (i >= total) return;
    int w = i % IMG_W;
    int h = (i / IMG_W) % IMG_H;
    int k = (i / (IMG_W * IMG_H)) % COUT;
    int n = i / (IMG_W * IMG_H * COUT);
    float s = 0.f;
    for (int c = 0; c < CIN; ++c) {
        #pragma unroll
        for (int dh = 0; dh < 3; ++dh) {
            int hh = h + dh - 1;
            if ((unsigned)hh >= (unsigned)IMG_H) continue;
            #pragma unroll
            for (int dw = 0; dw < 3; ++dw) {
                int ww = w + dw - 1;
                if ((unsigned)ww >= (unsigned)IMG_W) continue;
                s += x[((n * CIN + c) * IMG_H + hh) * IMG_W + ww] *
                     W[((k * CIN + c) * 3 + dh) * 3 + dw];
            }
        }
    }
    out[i] = s;
}

extern "C" void kernel_launch(void* const* d_in, const int* in_sizes, int n_in,
                              void* d_out, int out_size, void* d_ws, size_t ws_size,
                              hipStream_t stream) {
    const float* x = (const float*)d_in[0];
    const float* W = (const float*)d_in[1];
    float* out = (float*)d_out;

    const size_t wt_bytes = (size_t)9 * COUT * CIN * sizeof(bf16_t);
    if (ws_size >= wt_bytes) {
        bf16_t* wt = (bf16_t*)d_ws;
        wt_transform<<<dim3((9 * COUT * CIN) / 256), dim3(256), 0, stream>>>(W, wt);
        // grid: 4 w-tiles x 7 h-tiles x 32 images
        conv_mfma<<<dim3(IMG_W / TW + ((IMG_W % TW) ? 1 : 0) + 0 * 0 + 0, 7, 32) , dim3(256), 0, stream>>>(x, wt, out);
    } else {
        int total = 32 * COUT * IMG_H * IMG_W;
        conv_naive<<<dim3((total + 255) / 256), dim3(256), 0, stream>>>(x, W, out, total);
    }
}

// Round 2
// 308.763 us; speedup vs baseline: 1.1177x; 1.1177x over previous
//
#include <hip/hip_runtime.h>

typedef __bf16 bf16_t;
typedef __attribute__((ext_vector_type(8))) __bf16 bf16x8;
typedef __attribute__((ext_vector_type(4))) float f32x4;

#define IMG_H 56
#define IMG_W 56
#define CIN 256
#define COUT 256
#define TH 8      // output rows per block
#define TW 16     // output cols per block
#define XR 10     // input halo rows
#define XCOL 18   // input halo cols
#define CK 32     // c-chunk per stage
#define CPAD 40   // padded c dim in LDS (80B row stride, 16B aligned)

// ---- weight permute: W[k][c][3][3] fp32 -> wt2 in MFMA fragment order ------
// group u = t*8192 + ch*1024 + half*512 + fn*64 + lane ; 8 bf16 per group
// element j of group = W[k][c] tap t, k = half*128+fn*16+(lane&15),
//                      c = ch*32+(lane>>4)*8+j
__global__ void wt_permute(const float* __restrict__ W, bf16_t* __restrict__ wt2) {
    int u = blockIdx.x * 256 + threadIdx.x;   // 73728 groups total
    int lane = u & 63;
    int fn   = (u >> 6) & 7;
    int half = (u >> 9) & 1;
    int ch   = (u >> 10) & 7;
    int t    = u >> 13;
    int g = lane >> 4, pc = lane & 15;
    int k  = half * 128 + fn * 16 + pc;
    int cb = ch * 32 + g * 8;
    bf16x8 v;
    #pragma unroll
    for (int j = 0; j < 8; ++j)
        v[j] = (bf16_t)W[(k * CIN + cb + j) * 9 + t];
    *(bf16x8*)(wt2 + (size_t)u * 8) = v;
}

// ---- main conv: implicit GEMM, bf16 MFMA, B direct global->VGPR -------------
__global__ __launch_bounds__(256, 2)
void conv_mfma(const float* __restrict__ x, const bf16_t* __restrict__ wt2,
               float* __restrict__ out) {
    __shared__ bf16_t xs[XR * XCOL * CPAD];   // 14400 B

    const int tid  = threadIdx.x;
    const int lane = tid & 63;
    const int wid  = tid >> 6;
    const int n    = blockIdx.z;
    const int h0   = blockIdx.y * TH;
    const int w0   = blockIdx.x * TW;

    const int wm   = wid >> 1;      // wave row-half of pixel tile
    const int half = wid & 1;       // wave k-half (0:k<128, 1:k>=128)

    const int pc = lane & 15;
    const int g  = lane >> 4;
    const int c0 = g * 8;

    f32x4 acc[4][8] = {};           // 64 pixels x 128 channels per wave

    const bf16_t* wch_base = wt2 + (size_t)lane * 8 + (size_t)half * 4096;

    for (int ch = 0; ch < 8; ++ch) {
        __syncthreads();            // all waves done reading previous chunk
        // stage x halo tile for this c-chunk: xs[r][col][ci]
        for (int e = tid; e < XR * XCOL * CK; e += 256) {
            int col = e % XCOL;
            int r   = (e / XCOL) % XR;
            int ci  = e / (XCOL * XR);
            int hh = h0 - 1 + r;
            int ww = w0 - 1 + col;
            float v = 0.f;
            if ((unsigned)hh < (unsigned)IMG_H && (unsigned)ww < (unsigned)IMG_W)
                v = x[((n * CIN + ch * CK + ci) * IMG_H + hh) * IMG_W + ww];
            xs[(r * XCOL + col) * CPAD + ci] = (bf16_t)v;
        }
        __syncthreads();

        const bf16_t* wch = wch_base + (size_t)ch * 8192;   // (ch*2+half)*4096
        #pragma unroll 3
        for (int t = 0; t < 9; ++t) {
            const int dh = t / 3, dw = t % 3;
            const bf16_t* wp = wch + (size_t)t * 65536;
            bf16x8 b[8];
            #pragma unroll
            for (int fn = 0; fn < 8; ++fn)
                b[fn] = *(const bf16x8*)(wp + fn * 512);
            bf16x8 a[4];
            #pragma unroll
            for (int fm = 0; fm < 4; ++fm)
                a[fm] = *(const bf16x8*)&xs[((wm * 4 + fm + dh) * XCOL + (pc + dw)) * CPAD + c0];
            #pragma unroll
            for (int fm = 0; fm < 4; ++fm) {
                #pragma unroll
                for (int fn = 0; fn < 8; ++fn) {
                    acc[fm][fn] = __builtin_amdgcn_mfma_f32_16x16x32_bf16(
                        a[fm], b[fn], acc[fm][fn], 0, 0, 0);
                }
            }
        }
    }

    // epilogue: C/D layout col=lane&15 (k), row=(lane>>4)*4+reg (w offset)
    const int wcol = w0 + g * 4;
    if (wcol < IMG_W) {
        #pragma unroll
        for (int fm = 0; fm < 4; ++fm) {
            int hh = h0 + wm * 4 + fm;
            #pragma unroll
            for (int fn = 0; fn < 8; ++fn) {
                int k = half * 128 + fn * 16 + pc;
                *(f32x4*)&out[((n * COUT + k) * IMG_H + hh) * IMG_W + wcol] = acc[fm][fn];
            }
        }
    }
}

// ---- fallback (ws too small): naive fp32 conv --------------------------------
__global__ void conv_naive(const float* __restrict__ x, const float* __restrict__ W,
                           float* __restrict__ out, int total) {
    int i = blockIdx.x * 256 + threadIdx.x;
    if (i >= total) return;
    int w = i % IMG_W;
    int h = (i / IMG_W) % IMG_H;
    int k = (i / (IMG_W * IMG_H)) % COUT;
    int n = i / (IMG_W * IMG_H * COUT);
    float s = 0.f;
    for (int c = 0; c < CIN; ++c) {
        #pragma unroll
        for (int dh = 0; dh < 3; ++dh) {
            int hh = h + dh - 1;
            if ((unsigned)hh >= (unsigned)IMG_H) continue;
            #pragma unroll
            for (int dw = 0; dw < 3; ++dw) {
                int ww = w + dw - 1;
                if ((unsigned)ww >= (unsigned)IMG_W) continue;
                s += x[((n * CIN + c) * IMG_H + hh) * IMG_W + ww] *
                     W[((k * CIN + c) * 3 + dh) * 3 + dw];
            }
        }
    }
    out[i] = s;
}

extern "C" void kernel_launch(void* const* d_in, const int* in_sizes, int n_in,
                              void* d_out, int out_size, void* d_ws, size_t ws_size,
                              hipStream_t stream) {
    const float* x = (const float*)d_in[0];
    const float* W = (const float*)d_in[1];
    float* out = (float*)d_out;

    const size_t wt_bytes = (size_t)9 * COUT * CIN * sizeof(bf16_t);
    if (ws_size >= wt_bytes) {
        bf16_t* wt2 = (bf16_t*)d_ws;
        wt_permute<<<dim3(288), dim3(256), 0, stream>>>(W, wt2);
        conv_mfma<<<dim3(4, 7, 32), dim3(256), 0, stream>>>(x, wt2, out);
    } else {
        int total = 32 * COUT * IMG_H * IMG_W;
        conv_naive<<<dim3((total + 255) / 256), dim3(256), 0, stream>>>(x, W, out, total);
    }
}

// Round 3
// 236.715 us; speedup vs baseline: 1.4579x; 1.3044x over previous
//
#include <hip/hip_runtime.h>

typedef __bf16 bf16_t;
typedef __attribute__((ext_vector_type(2))) __bf16 bf16x2;
typedef __attribute__((ext_vector_type(8))) __bf16 bf16x8;
typedef __attribute__((ext_vector_type(4))) float f32x4;

#define IMG_H 56
#define IMG_W 56
#define CIN 256
#define COUT 256
#define TH 8        // output rows per block
#define TW 16       // output cols per block
#define XR 10       // halo rows
#define XCOL 18     // halo cols
#define CK 32       // c-chunk
#define PH 58       // padded H (1-px zero border)
#define PW 58       // padded W
#define NPIX (XR * XCOL)        // 180 pixels per halo tile
#define NUNIT (NPIX * 5)        // 900 16B-units (5th unit per pixel = pad)
#define NISSUE ((NUNIT + 63) / 64)  // 15 wave-issues
#define XS_ELEMS (NPIX * 40)    // 7200 bf16 per buffer (80B/pixel stride)

#define XBF_ELEMS ((size_t)32 * PH * PW * CIN)          // 27,557,888
#define XBF_BYTES (XBF_ELEMS * 2)                        // 55,115,776
#define WT_BYTES  ((size_t)9 * COUT * CIN * 2)           // 1,179,648

// ---- weight permute: W[k][c][3][3] fp32 -> wt2 in MFMA fragment order ------
__global__ void wt_permute(const float* __restrict__ W, bf16_t* __restrict__ wt2) {
    int u = blockIdx.x * 256 + threadIdx.x;   // 73728 groups
    int lane = u & 63;
    int fn   = (u >> 6) & 7;
    int half = (u >> 9) & 1;
    int ch   = (u >> 10) & 7;
    int t    = u >> 13;
    int g = lane >> 4, pc = lane & 15;
    int k  = half * 128 + fn * 16 + pc;
    int cb = ch * 32 + g * 8;
    bf16x8 v;
    #pragma unroll
    for (int j = 0; j < 8; ++j)
        v[j] = (bf16_t)W[(k * CIN + cb + j) * 9 + t];
    *(bf16x8*)(wt2 + (size_t)u * 8) = v;
}

// ---- x transpose: x[n][c][h][w] fp32 -> xbf[n][h+1][w+1][c] bf16 ------------
#define LSP 258   // LDS row stride (elems): 129 dwords -> conflict-free
__global__ __launch_bounds__(256)
void x_to_bf16(const float* __restrict__ x, bf16_t* __restrict__ xbf) {
    __shared__ bf16_t ls[IMG_W * LSP];
    const int n = blockIdx.y, h = blockIdx.x;
    const float* src = x + ((size_t)n * CIN * IMG_H + h) * IMG_W;
    for (int e = threadIdx.x; e < CIN * IMG_W; e += 256) {
        int c = e / IMG_W, w = e - c * IMG_W;
        ls[w * LSP + c] = (bf16_t)src[(size_t)c * (IMG_H * IMG_W) + w];
    }
    __syncthreads();
    bf16_t* dst = xbf + ((size_t)(n * PH + h + 1) * PW + 1) * CIN;
    for (int i = threadIdx.x; i < IMG_W * (CIN / 2); i += 256) {
        int w = i >> 7, cp = (i & 127) * 2;
        bf16x2 v;
        v[0] = ls[w * LSP + cp];
        v[1] = ls[w * LSP + cp + 1];
        *(bf16x2*)(dst + (size_t)w * CIN + cp) = v;
    }
}

// ---- main conv: implicit GEMM, async global_load_lds staging, dbuf LDS ------
__global__ __launch_bounds__(256, 2)
void conv_mfma(const bf16_t* __restrict__ xbf, const bf16_t* __restrict__ wt2,
               float* __restrict__ out) {
    __shared__ __align__(16) bf16_t xs[2][XS_ELEMS];   // 2 x 14400 B

    const int tid  = threadIdx.x;
    const int lane = tid & 63;
    const int wid  = tid >> 6;
    const int n    = blockIdx.z;
    const int h0   = blockIdx.y * TH;
    const int w0   = blockIdx.x * TW;

    const int wm   = wid >> 1;
    const int half = wid & 1;
    const int pc   = lane & 15;
    const int g    = lane >> 4;

    f32x4 acc[4][8] = {};
    const bf16_t* wfrag = wt2 + (size_t)lane * 8 + (size_t)half * 4096;
    const bf16_t* xn    = xbf + (size_t)n * (PH * PW * CIN);

    // async stage of c-chunk `ch` into buffer `buf`
    auto STAGE = [&](int buf, int ch) {
        #pragma unroll
        for (int j = wid; j < NISSUE; j += 4) {
            int u = j * 64 + lane;
            int p = u / 5;
            int q = u - p * 5;          // q==4 -> pad slot, skip
            if (u < NUNIT && q < 4) {
                int r   = p / XCOL;
                int col = p - r * XCOL;
                int w   = w0 + col;
                if (w > PW - 1) w = PW - 1;   // clamp into zero border (safe+correct)
                const bf16_t* src = xn + ((size_t)(h0 + r) * PW + w) * CIN + ch * CK + q * 8;
                __builtin_amdgcn_global_load_lds(
                    (const __attribute__((address_space(1))) void*)src,
                    (__attribute__((address_space(3))) void*)(&xs[buf][(size_t)j * 512]),
                    16, 0, 0);
            }
        }
    };

    STAGE(0, 0);
    __syncthreads();   // vmcnt(0) drain + barrier: buf0 ready

    for (int ch = 0; ch < 8; ++ch) {
        const int cur = ch & 1;
        if (ch < 7) STAGE(cur ^ 1, ch + 1);   // issue next chunk's loads early

        const bf16_t* wch = wfrag + (size_t)ch * 8192;
        #pragma unroll 3
        for (int t = 0; t < 9; ++t) {
            const int dh = t / 3, dw = t % 3;
            const bf16_t* wp = wch + (size_t)t * 65536;
            bf16x8 b[8];
            #pragma unroll
            for (int fn = 0; fn < 8; ++fn)
                b[fn] = *(const bf16x8*)(wp + fn * 512);
            bf16x8 a[4];
            #pragma unroll
            for (int fm = 0; fm < 4; ++fm)
                a[fm] = *(const bf16x8*)&xs[cur][((wm * 4 + fm + dh) * XCOL + pc + dw) * 40 + g * 8];
            #pragma unroll
            for (int fm = 0; fm < 4; ++fm) {
                #pragma unroll
                for (int fn = 0; fn < 8; ++fn) {
                    acc[fm][fn] = __builtin_amdgcn_mfma_f32_16x16x32_bf16(
                        a[fm], b[fn], acc[fm][fn], 0, 0, 0);
                }
            }
        }
        __syncthreads();  // all reads of xs[cur] done; next buffer's loads drained
    }

    // epilogue: C/D col=lane&15 (k), row=g*4+reg (w offset)
    const int wcol = w0 + g * 4;
    if (wcol < IMG_W) {
        #pragma unroll
        for (int fm = 0; fm < 4; ++fm) {
            int hh = h0 + wm * 4 + fm;
            #pragma unroll
            for (int fn = 0; fn < 8; ++fn) {
                int k = half * 128 + fn * 16 + pc;
                *(f32x4*)&out[((n * COUT + k) * IMG_H + hh) * IMG_W + wcol] = acc[fm][fn];
            }
        }
    }
}

// ---- mid fallback: round-2 conv (B direct global, scalar x staging) ---------
#define CPAD 40
__global__ __launch_bounds__(256, 2)
void conv_mfma_v2(const float* __restrict__ x, const bf16_t* __restrict__ wt2,
                  float* __restrict__ out) {
    __shared__ bf16_t xsl[XR * XCOL * CPAD];
    const int tid  = threadIdx.x;
    const int lane = tid & 63;
    const int wid  = tid >> 6;
    const int n    = blockIdx.z;
    const int h0   = blockIdx.y * TH;
    const int w0   = blockIdx.x * TW;
    const int wm   = wid >> 1;
    const int half = wid & 1;
    const int pc = lane & 15;
    const int g  = lane >> 4;
    const int c0 = g * 8;
    f32x4 acc[4][8] = {};
    const bf16_t* wch_base = wt2 + (size_t)lane * 8 + (size_t)half * 4096;
    for (int ch = 0; ch < 8; ++ch) {
        __syncthreads();
        for (int e = tid; e < XR * XCOL * CK; e += 256) {
            int col = e % XCOL;
            int r   = (e / XCOL) % XR;
            int ci  = e / (XCOL * XR);
            int hh = h0 - 1 + r;
            int ww = w0 - 1 + col;
            float v = 0.f;
            if ((unsigned)hh < (unsigned)IMG_H && (unsigned)ww < (unsigned)IMG_W)
                v = x[((n * CIN + ch * CK + ci) * IMG_H + hh) * IMG_W + ww];
            xsl[(r * XCOL + col) * CPAD + ci] = (bf16_t)v;
        }
        __syncthreads();
        const bf16_t* wch = wch_base + (size_t)ch * 8192;
        #pragma unroll 3
        for (int t = 0; t < 9; ++t) {
            const int dh = t / 3, dw = t % 3;
            const bf16_t* wp = wch + (size_t)t * 65536;
            bf16x8 b[8];
            #pragma unroll
            for (int fn = 0; fn < 8; ++fn)
                b[fn] = *(const bf16x8*)(wp + fn * 512);
            bf16x8 a[4];
            #pragma unroll
            for (int fm = 0; fm < 4; ++fm)
                a[fm] = *(const bf16x8*)&xsl[((wm * 4 + fm + dh) * XCOL + (pc + dw)) * CPAD + c0];
            #pragma unroll
            for (int fm = 0; fm < 4; ++fm)
                #pragma unroll
                for (int fn = 0; fn < 8; ++fn)
                    acc[fm][fn] = __builtin_amdgcn_mfma_f32_16x16x32_bf16(
                        a[fm], b[fn], acc[fm][fn], 0, 0, 0);
        }
    }
    const int wcol = w0 + g * 4;
    if (wcol < IMG_W) {
        #pragma unroll
        for (int fm = 0; fm < 4; ++fm) {
            int hh = h0 + wm * 4 + fm;
            #pragma unroll
            for (int fn = 0; fn < 8; ++fn) {
                int k = half * 128 + fn * 16 + pc;
                *(f32x4*)&out[((n * COUT + k) * IMG_H + hh) * IMG_W + wcol] = acc[fm][fn];
            }
        }
    }
}

// ---- last-resort fallback: naive fp32 conv -----------------------------------
__global__ void conv_naive(const float* __restrict__ x, const float* __restrict__ W,
                           float* __restrict__ out, int total) {
    int i = blockIdx.x * 256 + threadIdx.x;
    if (i >= total) return;
    int w = i % IMG_W;
    int h = (i / IMG_W) % IMG_H;
    int k = (i / (IMG_W * IMG_H)) % COUT;
    int n = i / (IMG_W * IMG_H * COUT);
    float s = 0.f;
    for (int c = 0; c < CIN; ++c) {
        #pragma unroll
        for (int dh = 0; dh < 3; ++dh) {
            int hh = h + dh - 1;
            if ((unsigned)hh >= (unsigned)IMG_H) continue;
            #pragma unroll
            for (int dw = 0; dw < 3; ++dw) {
                int ww = w + dw - 1;
                if ((unsigned)ww >= (unsigned)IMG_W) continue;
                s += x[((n * CIN + c) * IMG_H + hh) * IMG_W + ww] *
                     W[((k * CIN + c) * 3 + dh) * 3 + dw];
            }
        }
    }
    out[i] = s;
}

extern "C" void kernel_launch(void* const* d_in, const int* in_sizes, int n_in,
                              void* d_out, int out_size, void* d_ws, size_t ws_size,
                              hipStream_t stream) {
    const float* x = (const float*)d_in[0];
    const float* W = (const float*)d_in[1];
    float* out = (float*)d_out;

    if (ws_size >= XBF_BYTES + WT_BYTES) {
        bf16_t* xbf = (bf16_t*)d_ws;
        bf16_t* wt2 = (bf16_t*)((char*)d_ws + XBF_BYTES);
        hipMemsetAsync(d_ws, 0, XBF_BYTES, stream);   // zero halo border
        wt_permute<<<dim3(288), dim3(256), 0, stream>>>(W, wt2);
        x_to_bf16<<<dim3(IMG_H, 32), dim3(256), 0, stream>>>(x, xbf);
        conv_mfma<<<dim3(4, 7, 32), dim3(256), 0, stream>>>(xbf, wt2, out);
    } else if (ws_size >= WT_BYTES) {
        bf16_t* wt2 = (bf16_t*)d_ws;
        wt_permute<<<dim3(288), dim3(256), 0, stream>>>(W, wt2);
        conv_mfma_v2<<<dim3(4, 7, 32), dim3(256), 0, stream>>>(x, wt2, out);
    } else {
        int total = 32 * COUT * IMG_H * IMG_W;
        conv_naive<<<dim3((total + 255) / 256), dim3(256), 0, stream>>>(x, W, out, total);
    }
}

// Round 5
// 167.415 us; speedup vs baseline: 2.0614x; 1.4139x over previous
//
#include <hip/hip_runtime.h>

typedef __bf16 bf16_t;
typedef __attribute__((ext_vector_type(8))) __bf16 bf16x8;
typedef __attribute__((ext_vector_type(4))) float f32x4;

#define IMG_H 56
#define IMG_W 56
#define CIN 256
#define COUT 256
#define TH 8        // output rows per block
#define TW 16       // output cols per block
#define XR 10       // halo rows
#define XCOL 18     // halo cols
#define CK 32       // c-chunk
#define PH 58       // padded H (1-px zero border)
#define PW 58       // padded W
#define NPIX (XR * XCOL)            // 180 pixels per halo tile
#define NUNIT (NPIX * 5)            // 900 16B-units (5th = pad, skipped)
#define NISSUE ((NUNIT + 63) / 64)  // 15 wave-issues
#define XS_ELEMS (NPIX * 40)        // 7200 bf16 per buffer (80B/pixel)

#define XBF_BYTES ((size_t)32 * PH * PW * CIN * 2)   // 55,115,776
#define WT_BYTES  ((size_t)9 * COUT * CIN * 2)       // 1,179,648

// ---- weight permute: W[k][c][3][3] fp32 -> wt2 in MFMA fragment order ------
// elem offset = t*65536 + ch*8192 + half*4096 + fn*512 + lane*8 + j
// maps to W[k][c] tap t with k=half*128+fn*16+(lane&15), c=ch*32+(lane>>4)*8+j
__global__ void wt_permute(const float* __restrict__ W, bf16_t* __restrict__ wt2) {
    int u = blockIdx.x * 256 + threadIdx.x;   // 73728 groups
    int lane = u & 63;
    int fn   = (u >> 6) & 7;
    int half = (u >> 9) & 1;
    int ch   = (u >> 10) & 7;
    int t    = u >> 13;
    int g = lane >> 4, pc = lane & 15;
    int k  = half * 128 + fn * 16 + pc;
    int cb = ch * 32 + g * 8;
    bf16x8 v;
    #pragma unroll
    for (int j = 0; j < 8; ++j)
        v[j] = (bf16_t)W[(k * CIN + cb + j) * 9 + t];
    *(bf16x8*)(wt2 + (size_t)u * 8) = v;
}

// ---- x transpose: x[n][c][h][w] fp32 -> xbf[n][ph][pw][c] bf16, borders=0 ---
#define LSP 258   // LDS row stride (elems)
__global__ __launch_bounds__(256)
void x_to_bf16(const float* __restrict__ x, bf16_t* __restrict__ xbf) {
    __shared__ bf16_t ls[IMG_W * LSP];
    const int n = blockIdx.y, ph = blockIdx.x;   // ph: 0..57 padded row
    bf16_t* drow = xbf + (size_t)(n * PH + ph) * PW * CIN;
    const f32x4 zf = {0.f, 0.f, 0.f, 0.f};
    if (ph == 0 || ph == PH - 1) {
        for (int i = threadIdx.x; i < PW * CIN / 8; i += 256)
            ((f32x4*)drow)[i] = zf;          // zero whole padded row
        return;
    }
    // zero left (w=0) and right (w=57) border pixels
    for (int i = threadIdx.x; i < 2 * CIN / 8; i += 256) {
        int side = i >> 5, off = i & 31;
        ((f32x4*)(drow + (side ? (size_t)(PW - 1) * CIN : 0)))[off] = zf;
    }
    const int h = ph - 1;
    const float* src = x + ((size_t)n * CIN * IMG_H + h) * IMG_W;
    for (int e = threadIdx.x; e < CIN * IMG_W; e += 256) {
        int c = e / IMG_W, w = e - c * IMG_W;
        ls[w * LSP + c] = (bf16_t)src[(size_t)c * (IMG_H * IMG_W) + w];
    }
    __syncthreads();
    bf16_t* dst = drow + CIN;    // w=1 (first interior col)
    for (int i = threadIdx.x; i < IMG_W * (CIN / 8); i += 256) {
        int w = i >> 5, cp = (i & 31) * 8;
        bf16x8 v;
        #pragma unroll
        for (int j = 0; j < 8; ++j) v[j] = ls[w * LSP + cp + j];
        *(bf16x8*)(dst + (size_t)w * CIN + cp) = v;
    }
}

// ---- main conv: implicit GEMM, async dbuf x-staging, B reg-pipelined --------
__global__ __launch_bounds__(256, 2)
void conv_mfma(const bf16_t* __restrict__ xbf, const bf16_t* __restrict__ wt2,
               float* __restrict__ out) {
    __shared__ __align__(16) bf16_t xs[2][XS_ELEMS];   // 2 x 14400 B

    const int tid  = threadIdx.x;
    const int lane = tid & 63;
    const int wid  = tid >> 6;
    const int n    = blockIdx.z;
    const int h0   = blockIdx.y * TH;
    const int w0   = blockIdx.x * TW;

    const int wm   = wid >> 1;
    const int half = wid & 1;
    const int pc   = lane & 15;
    const int g    = lane >> 4;

    f32x4 acc[4][8] = {};
    const bf16_t* wfrag = wt2 + (size_t)lane * 8 + (size_t)half * 4096;
    const bf16_t* xn    = xbf + (size_t)n * (PH * PW * CIN);

    // precomputed staging descriptors: 4 issue-slots per thread
    const bf16_t* ssrc[4];
    int sdst[4];
    bool sval[4];
    #pragma unroll
    for (int s = 0; s < 4; ++s) {
        int j = wid + s * 4;
        int u = j * 64 + lane;
        int p = u / 5, q = u - p * 5;
        sval[s] = (j < NISSUE) && (u < NUNIT) && (q < 4);   // <-- u<NUNIT restored
        int r = p / XCOL, col = p - r * XCOL;
        int w = w0 + col; if (w > PW - 1) w = PW - 1;   // clamp into zero border
        int rr = (r > XR - 1) ? (XR - 1) : r;           // clamp row for inactive lanes
        ssrc[s] = xn + ((size_t)(h0 + rr) * PW + w) * CIN + q * 8;
        sdst[s] = j * 512;                              // wave-uniform LDS base
    }

    auto STAGE = [&](int buf, int ch) {
        #pragma unroll
        for (int s = 0; s < 4; ++s)
            if (sval[s])
                __builtin_amdgcn_global_load_lds(
                    (const __attribute__((address_space(1))) void*)(ssrc[s] + ch * CK),
                    (__attribute__((address_space(3))) void*)(&xs[buf][sdst[s]]),
                    16, 0, 0);
    };

    STAGE(0, 0);
    __syncthreads();   // buf0 ready

    for (int ch = 0; ch < 8; ++ch) {
        const int cur = ch & 1;
        const bf16_t* wch = wfrag + (size_t)ch * 8192;

        // tap-0 B loads FIRST (so their wait isn't behind STAGE in vmcnt FIFO)
        bf16x8 bcur[8], bnext[8];
        #pragma unroll
        for (int fn = 0; fn < 8; ++fn)
            bcur[fn] = *(const bf16x8*)(wch + fn * 512);

        if (ch < 7) STAGE(cur ^ 1, ch + 1);   // async prefetch next chunk (drains by barrier)

        #pragma unroll
        for (int t = 0; t < 9; ++t) {
            const int dh = t / 3, dw = t % 3;
            if (t < 8) {   // prefetch next tap's B fragments (reg dbuf)
                const bf16_t* wp = wch + (size_t)(t + 1) * 65536;
                #pragma unroll
                for (int fn = 0; fn < 8; ++fn)
                    bnext[fn] = *(const bf16x8*)(wp + fn * 512);
            }
            bf16x8 a[4];
            #pragma unroll
            for (int fm = 0; fm < 4; ++fm)
                a[fm] = *(const bf16x8*)&xs[cur][((wm * 4 + fm + dh) * XCOL + pc + dw) * 40 + g * 8];
            #pragma unroll
            for (int fm = 0; fm < 4; ++fm)
                #pragma unroll
                for (int fn = 0; fn < 8; ++fn)
                    acc[fm][fn] = __builtin_amdgcn_mfma_f32_16x16x32_bf16(
                        a[fm], bcur[fn], acc[fm][fn], 0, 0, 0);
            if (t < 8) {
                #pragma unroll
                for (int fn = 0; fn < 8; ++fn) bcur[fn] = bnext[fn];  // SSA rename
            }
        }
        __syncthreads();   // xs[cur] free; next buffer's loads drained
    }

    // epilogue: C/D col=lane&15 (k), row=g*4+reg (w offset)
    const int wcol = w0 + g * 4;
    if (wcol < IMG_W) {
        #pragma unroll
        for (int fm = 0; fm < 4; ++fm) {
            int hh = h0 + wm * 4 + fm;
            #pragma unroll
            for (int fn = 0; fn < 8; ++fn) {
                int k = half * 128 + fn * 16 + pc;
                *(f32x4*)&out[((n * COUT + k) * IMG_H + hh) * IMG_W + wcol] = acc[fm][fn];
            }
        }
    }
}

// ---- mid fallback: B direct global, scalar x staging (round-2 proven) -------
#define CPAD 40
__global__ __launch_bounds__(256, 2)
void conv_mfma_v2(const float* __restrict__ x, const bf16_t* __restrict__ wt2,
                  float* __restrict__ out) {
    __shared__ bf16_t xsl[XR * XCOL * CPAD];
    const int tid  = threadIdx.x;
    const int lane = tid & 63;
    const int wid  = tid >> 6;
    const int n    = blockIdx.z;
    const int h0   = blockIdx.y * TH;
    const int w0   = blockIdx.x * TW;
    const int wm   = wid >> 1;
    const int half = wid & 1;
    const int pc = lane & 15;
    const int g  = lane >> 4;
    const int c0 = g * 8;
    f32x4 acc[4][8] = {};
    const bf16_t* wch_base = wt2 + (size_t)lane * 8 + (size_t)half * 4096;
    for (int ch = 0; ch < 8; ++ch) {
        __syncthreads();
        for (int e = tid; e < XR * XCOL * CK; e += 256) {
            int col = e % XCOL;
            int r   = (e / XCOL) % XR;
            int ci  = e / (XCOL * XR);
            int hh = h0 - 1 + r;
            int ww = w0 - 1 + col;
            float v = 0.f;
            if ((unsigned)hh < (unsigned)IMG_H && (unsigned)ww < (unsigned)IMG_W)
                v = x[((n * CIN + ch * CK + ci) * IMG_H + hh) * IMG_W + ww];
            xsl[(r * XCOL + col) * CPAD + ci] = (bf16_t)v;
        }
        __syncthreads();
        const bf16_t* wch = wch_base + (size_t)ch * 8192;
        #pragma unroll 3
        for (int t = 0; t < 9; ++t) {
            const int dh = t / 3, dw = t % 3;
            const bf16_t* wp = wch + (size_t)t * 65536;
            bf16x8 b[8];
            #pragma unroll
            for (int fn = 0; fn < 8; ++fn)
                b[fn] = *(const bf16x8*)(wp + fn * 512);
            bf16x8 a[4];
            #pragma unroll
            for (int fm = 0; fm < 4; ++fm)
                a[fm] = *(const bf16x8*)&xsl[((wm * 4 + fm + dh) * XCOL + (pc + dw)) * CPAD + c0];
            #pragma unroll
            for (int fm = 0; fm < 4; ++fm)
                #pragma unroll
                for (int fn = 0; fn < 8; ++fn)
                    acc[fm][fn] = __builtin_amdgcn_mfma_f32_16x16x32_bf16(
                        a[fm], b[fn], acc[fm][fn], 0, 0, 0);
        }
    }
    const int wcol = w0 + g * 4;
    if (wcol < IMG_W) {
        #pragma unroll
        for (int fm = 0; fm < 4; ++fm) {
            int hh = h0 + wm * 4 + fm;
            #pragma unroll
            for (int fn = 0; fn < 8; ++fn) {
                int k = half * 128 + fn * 16 + pc;
                *(f32x4*)&out[((n * COUT + k) * IMG_H + hh) * IMG_W + wcol] = acc[fm][fn];
            }
        }
    }
}

// ---- last-resort fallback: naive fp32 conv ----------------------------------
__global__ void conv_naive(const float* __restrict__ x, const float* __restrict__ W,
                           float* __restrict__ out, int total) {
    int i = blockIdx.x * 256 + threadIdx.x;
    if (i >= total) return;
    int w = i % IMG_W;
    int h = (i / IMG_W) % IMG_H;
    int k = (i / (IMG_W * IMG_H)) % COUT;
    int n = i / (IMG_W * IMG_H * COUT);
    float s = 0.f;
    for (int c = 0; c < CIN; ++c) {
        #pragma unroll
        for (int dh = 0; dh < 3; ++dh) {
            int hh = h + dh - 1;
            if ((unsigned)hh >= (unsigned)IMG_H) continue;
            #pragma unroll
            for (int dw = 0; dw < 3; ++dw) {
                int ww = w + dw - 1;
                if ((unsigned)ww >= (unsigned)IMG_W) continue;
                s += x[((n * CIN + c) * IMG_H + hh) * IMG_W + ww] *
                     W[((k * CIN + c) * 3 + dh) * 3 + dw];
            }
        }
    }
    out[i] = s;
}

extern "C" void kernel_launch(void* const* d_in, const int* in_sizes, int n_in,
                              void* d_out, int out_size, void* d_ws, size_t ws_size,
                              hipStream_t stream) {
    const float* x = (const float*)d_in[0];
    const float* W = (const float*)d_in[1];
    float* out = (float*)d_out;

    if (ws_size >= XBF_BYTES + WT_BYTES) {
        bf16_t* xbf = (bf16_t*)d_ws;
        bf16_t* wt2 = (bf16_t*)((char*)d_ws + XBF_BYTES);
        wt_permute<<<dim3(288), dim3(256), 0, stream>>>(W, wt2);
        x_to_bf16<<<dim3(PH, 32), dim3(256), 0, stream>>>(x, xbf);   // writes borders
        conv_mfma<<<dim3(4, 7, 32), dim3(256), 0, stream>>>(xbf, wt2, out);
    } else if (ws_size >= WT_BYTES) {
        bf16_t* wt2 = (bf16_t*)d_ws;
        wt_permute<<<dim3(288), dim3(256), 0, stream>>>(W, wt2);
        conv_mfma_v2<<<dim3(4, 7, 32), dim3(256), 0, stream>>>(x, wt2, out);
    } else {
        int total = 32 * COUT * IMG_H * IMG_W;
        conv_naive<<<dim3((total + 255) / 256), dim3(256), 0, stream>>>(x, W, out, total);
    }
}

// Round 6
// 164.664 us; speedup vs baseline: 2.0959x; 1.0167x over previous
//
#include <hip/hip_runtime.h>

typedef __bf16 bf16_t;
typedef __attribute__((ext_vector_type(8))) __bf16 bf16x8;
typedef __attribute__((ext_vector_type(4))) float f32x4;

#define IMG_H 56
#define IMG_W 56
#define CIN 256
#define COUT 256
#define TH 8        // output rows per block
#define TW 16       // output cols per block
#define XR 10       // halo rows
#define XCOL 18     // halo cols
#define CK 32       // c-chunk
#define PH 58       // padded H (1-px zero border)
#define PW 58       // padded W
#define NPIX (XR * XCOL)            // 180 pixels per halo tile
#define NUNIT (NPIX * 5)            // 900 16B-units (5th = pad, skipped)
#define NISSUE ((NUNIT + 63) / 64)  // 15 wave-issues
#define XS_ELEMS (NPIX * 40)        // 7200 bf16 per buffer (80B/pixel)

#define XBF_BYTES ((size_t)32 * PH * PW * CIN * 2)   // 55,115,776
#define WT_BYTES  ((size_t)9 * COUT * CIN * 2)       // 1,179,648

// ---- weight permute: W[k][c][3][3] fp32 -> wt2 in MFMA fragment order ------
// elem offset = t*65536 + ch*8192 + half*4096 + fn*512 + lane*8 + j
// maps to W[k][c] tap t with k=half*128+fn*16+(lane&15), c=ch*32+(lane>>4)*8+j
__global__ void wt_permute(const float* __restrict__ W, bf16_t* __restrict__ wt2) {
    int u = blockIdx.x * 256 + threadIdx.x;   // 73728 groups
    int lane = u & 63;
    int fn   = (u >> 6) & 7;
    int half = (u >> 9) & 1;
    int ch   = (u >> 10) & 7;
    int t    = u >> 13;
    int g = lane >> 4, pc = lane & 15;
    int k  = half * 128 + fn * 16 + pc;
    int cb = ch * 32 + g * 8;
    bf16x8 v;
    #pragma unroll
    for (int j = 0; j < 8; ++j)
        v[j] = (bf16_t)W[(k * CIN + cb + j) * 9 + t];
    *(bf16x8*)(wt2 + (size_t)u * 8) = v;
}

// ---- x transpose: x[n][c][h][w] fp32 -> xbf[n][ph][pw][c] bf16, borders=0 ---
#define LSP 258   // LDS row stride (elems)
__global__ __launch_bounds__(256)
void x_to_bf16(const float* __restrict__ x, bf16_t* __restrict__ xbf) {
    __shared__ bf16_t ls[IMG_W * LSP];
    const int n = blockIdx.y, ph = blockIdx.x;   // ph: 0..57 padded row
    bf16_t* drow = xbf + (size_t)(n * PH + ph) * PW * CIN;
    const f32x4 zf = {0.f, 0.f, 0.f, 0.f};
    if (ph == 0 || ph == PH - 1) {
        for (int i = threadIdx.x; i < PW * CIN / 8; i += 256)
            ((f32x4*)drow)[i] = zf;          // zero whole padded row
        return;
    }
    // zero left (w=0) and right (w=57) border pixels
    for (int i = threadIdx.x; i < 2 * CIN / 8; i += 256) {
        int side = i >> 5, off = i & 31;
        ((f32x4*)(drow + (side ? (size_t)(PW - 1) * CIN : 0)))[off] = zf;
    }
    const int h = ph - 1;
    const float* src = x + ((size_t)n * CIN * IMG_H + h) * IMG_W;
    for (int e = threadIdx.x; e < CIN * IMG_W; e += 256) {
        int c = e / IMG_W, w = e - c * IMG_W;
        ls[w * LSP + c] = (bf16_t)src[(size_t)c * (IMG_H * IMG_W) + w];
    }
    __syncthreads();
    bf16_t* dst = drow + CIN;    // w=1 (first interior col)
    for (int i = threadIdx.x; i < IMG_W * (CIN / 8); i += 256) {
        int w = i >> 5, cp = (i & 31) * 8;
        bf16x8 v;
        #pragma unroll
        for (int j = 0; j < 8; ++j) v[j] = ls[w * LSP + cp + j];
        *(bf16x8*)(dst + (size_t)w * CIN + cp) = v;
    }
}

// ---- main conv: implicit GEMM; wave = 128 px x 64 k (FM=8, FN=4) ------------
__global__ __launch_bounds__(256, 2)
void conv_mfma(const bf16_t* __restrict__ xbf, const bf16_t* __restrict__ wt2,
               float* __restrict__ out) {
    __shared__ __align__(16) bf16_t xs[2][XS_ELEMS];   // 2 x 14400 B

    const int tid  = threadIdx.x;
    const int lane = tid & 63;
    const int kq   = tid >> 6;      // wave k-quarter (0..3)
    const int n    = blockIdx.z;
    const int h0   = blockIdx.y * TH;
    const int w0   = blockIdx.x * TW;

    const int pc = lane & 15;
    const int g  = lane >> 4;

    f32x4 acc[8][4] = {};           // 128 pixels x 64 channels per wave
    // B fragment base for this wave's k-quarter:
    //   half = kq>>1, fn = (kq&1)*4 + q  ->  + (kq>>1)*4096 + (kq&1)*2048 + q*512
    const bf16_t* wfrag = wt2 + (size_t)lane * 8 + (size_t)(kq >> 1) * 4096
                              + (size_t)(kq & 1) * 2048;
    const bf16_t* xn = xbf + (size_t)n * (PH * PW * CIN);

    // precomputed staging descriptors: 4 issue-slots per thread
    const bf16_t* ssrc[4];
    int sdst[4];
    bool sval[4];
    #pragma unroll
    for (int s = 0; s < 4; ++s) {
        int j = kq + s * 4;
        int u = j * 64 + lane;
        int p = u / 5, q = u - p * 5;
        sval[s] = (j < NISSUE) && (u < NUNIT) && (q < 4);
        int r = p / XCOL, col = p - r * XCOL;
        int w = w0 + col; if (w > PW - 1) w = PW - 1;   // clamp into zero border
        int rr = (r > XR - 1) ? (XR - 1) : r;           // clamp for inactive lanes
        ssrc[s] = xn + ((size_t)(h0 + rr) * PW + w) * CIN + q * 8;
        sdst[s] = j * 512;                              // wave-uniform LDS base
    }

    auto STAGE = [&](int buf, int ch) {
        #pragma unroll
        for (int s = 0; s < 4; ++s)
            if (sval[s])
                __builtin_amdgcn_global_load_lds(
                    (const __attribute__((address_space(1))) void*)(ssrc[s] + ch * CK),
                    (__attribute__((address_space(3))) void*)(&xs[buf][sdst[s]]),
                    16, 0, 0);
    };

    STAGE(0, 0);
    __syncthreads();   // buf0 ready

    for (int ch = 0; ch < 8; ++ch) {
        const int cur = ch & 1;
        const bf16_t* wch = wfrag + (size_t)ch * 8192;

        // tap-0 B loads FIRST (their wait must not sit behind STAGE in vmcnt FIFO)
        bf16x8 bcur[4], bnext[4];
        #pragma unroll
        for (int q = 0; q < 4; ++q)
            bcur[q] = *(const bf16x8*)(wch + q * 512);

        if (ch < 7) STAGE(cur ^ 1, ch + 1);   // async prefetch next chunk

        #pragma unroll
        for (int t = 0; t < 9; ++t) {
            const int dh = t / 3, dw = t % 3;
            if (t < 8) {   // prefetch next tap's B fragments (reg dbuf)
                const bf16_t* wp = wch + (size_t)(t + 1) * 65536;
                #pragma unroll
                for (int q = 0; q < 4; ++q)
                    bnext[q] = *(const bf16x8*)(wp + q * 512);
            }
            bf16x8 a[8];
            #pragma unroll
            for (int fm = 0; fm < 8; ++fm)
                a[fm] = *(const bf16x8*)&xs[cur][((fm + dh) * XCOL + pc + dw) * 40 + g * 8];
            #pragma unroll
            for (int fm = 0; fm < 8; ++fm)
                #pragma unroll
                for (int q = 0; q < 4; ++q)
                    acc[fm][q] = __builtin_amdgcn_mfma_f32_16x16x32_bf16(
                        a[fm], bcur[q], acc[fm][q], 0, 0, 0);
            if (t < 8) {
                #pragma unroll
                for (int q = 0; q < 4; ++q) bcur[q] = bnext[q];  // SSA rename
            }
        }
        __syncthreads();   // xs[cur] free; next buffer's loads drained
    }

    // epilogue: C/D col=lane&15 (within-16 k), row=g*4+reg (w offset)
    const int wcol = w0 + g * 4;
    if (wcol < IMG_W) {
        #pragma unroll
        for (int fm = 0; fm < 8; ++fm) {
            int hh = h0 + fm;
            #pragma unroll
            for (int q = 0; q < 4; ++q) {
                int k = kq * 64 + q * 16 + pc;
                *(f32x4*)&out[((n * COUT + k) * IMG_H + hh) * IMG_W + wcol] = acc[fm][q];
            }
        }
    }
}

// ---- mid fallback: B direct global, scalar x staging (round-2 proven) -------
#define CPAD 40
__global__ __launch_bounds__(256, 2)
void conv_mfma_v2(const float* __restrict__ x, const bf16_t* __restrict__ wt2,
                  float* __restrict__ out) {
    __shared__ bf16_t xsl[XR * XCOL * CPAD];
    const int tid  = threadIdx.x;
    const int lane = tid & 63;
    const int wid  = tid >> 6;
    const int n    = blockIdx.z;
    const int h0   = blockIdx.y * TH;
    const int w0   = blockIdx.x * TW;
    const int wm   = wid >> 1;
    const int half = wid & 1;
    const int pc = lane & 15;
    const int g  = lane >> 4;
    const int c0 = g * 8;
    f32x4 acc[4][8] = {};
    const bf16_t* wch_base = wt2 + (size_t)lane * 8 + (size_t)half * 4096;
    for (int ch = 0; ch < 8; ++ch) {
        __syncthreads();
        for (int e = tid; e < XR * XCOL * CK; e += 256) {
            int col = e % XCOL;
            int r   = (e / XCOL) % XR;
            int ci  = e / (XCOL * XR);
            int hh = h0 - 1 + r;
            int ww = w0 - 1 + col;
            float v = 0.f;
            if ((unsigned)hh < (unsigned)IMG_H && (unsigned)ww < (unsigned)IMG_W)
                v = x[((n * CIN + ch * CK + ci) * IMG_H + hh) * IMG_W + ww];
            xsl[(r * XCOL + col) * CPAD + ci] = (bf16_t)v;
        }
        __syncthreads();
        const bf16_t* wch = wch_base + (size_t)ch * 8192;
        #pragma unroll 3
        for (int t = 0; t < 9; ++t) {
            const int dh = t / 3, dw = t % 3;
            const bf16_t* wp = wch + (size_t)t * 65536;
            bf16x8 b[8];
            #pragma unroll
            for (int fn = 0; fn < 8; ++fn)
                b[fn] = *(const bf16x8*)(wp + fn * 512);
            bf16x8 a[4];
            #pragma unroll
            for (int fm = 0; fm < 4; ++fm)
                a[fm] = *(const bf16x8*)&xsl[((wm * 4 + fm + dh) * XCOL + (pc + dw)) * CPAD + c0];
            #pragma unroll
            for (int fm = 0; fm < 4; ++fm)
                #pragma unroll
                for (int fn = 0; fn < 8; ++fn)
                    acc[fm][fn] = __builtin_amdgcn_mfma_f32_16x16x32_bf16(
                        a[fm], b[fn], acc[fm][fn], 0, 0, 0);
        }
    }
    const int wcol = w0 + g * 4;
    if (wcol < IMG_W) {
        #pragma unroll
        for (int fm = 0; fm < 4; ++fm) {
            int hh = h0 + wm * 4 + fm;
            #pragma unroll
            for (int fn = 0; fn < 8; ++fn) {
                int k = half * 128 + fn * 16 + pc;
                *(f32x4*)&out[((n * COUT + k) * IMG_H + hh) * IMG_W + wcol] = acc[fm][fn];
            }
        }
    }
}

// ---- last-resort fallback: naive fp32 conv ----------------------------------
__global__ void conv_naive(const float* __restrict__ x, const float* __restrict__ W,
                           float* __restrict__ out, int total) {
    int i = blockIdx.x * 256 + threadIdx.x;
    if (i >= total) return;
    int w = i % IMG_W;
    int h = (i / IMG_W) % IMG_H;
    int k = (i / (IMG_W * IMG_H)) % COUT;
    int n = i / (IMG_W * IMG_H * COUT);
    float s = 0.f;
    for (int c = 0; c < CIN; ++c) {
        #pragma unroll
        for (int dh = 0; dh < 3; ++dh) {
            int hh = h + dh - 1;
            if ((unsigned)hh >= (unsigned)IMG_H) continue;
            #pragma unroll
            for (int dw = 0; dw < 3; ++dw) {
                int ww = w + dw - 1;
                if ((unsigned)ww >= (unsigned)IMG_W) continue;
                s += x[((n * CIN + c) * IMG_H + hh) * IMG_W + ww] *
                     W[((k * CIN + c) * 3 + dh) * 3 + dw];
            }
        }
    }
    out[i] = s;
}

extern "C" void kernel_launch(void* const* d_in, const int* in_sizes, int n_in,
                              void* d_out, int out_size, void* d_ws, size_t ws_size,
                              hipStream_t stream) {
    const float* x = (const float*)d_in[0];
    const float* W = (const float*)d_in[1];
    float* out = (float*)d_out;

    if (ws_size >= XBF_BYTES + WT_BYTES) {
        bf16_t* xbf = (bf16_t*)d_ws;
        bf16_t* wt2 = (bf16_t*)((char*)d_ws + XBF_BYTES);
        wt_permute<<<dim3(288), dim3(256), 0, stream>>>(W, wt2);
        x_to_bf16<<<dim3(PH, 32), dim3(256), 0, stream>>>(x, xbf);   // writes borders
        conv_mfma<<<dim3(4, 7, 32), dim3(256), 0, stream>>>(xbf, wt2, out);
    } else if (ws_size >= WT_BYTES) {
        bf16_t* wt2 = (bf16_t*)d_ws;
        wt_permute<<<dim3(288), dim3(256), 0, stream>>>(W, wt2);
        conv_mfma_v2<<<dim3(4, 7, 32), dim3(256), 0, stream>>>(x, wt2, out);
    } else {
        int total = 32 * COUT * IMG_H * IMG_W;
        conv_naive<<<dim3((total + 255) / 256), dim3(256), 0, stream>>>(x, W, out, total);
    }
}

// Round 7
// 160.213 us; speedup vs baseline: 2.1541x; 1.0278x over previous
//
#include <hip/hip_runtime.h>

typedef __bf16 bf16_t;
typedef __attribute__((ext_vector_type(8))) __bf16 bf16x8;
typedef __attribute__((ext_vector_type(4))) float f32x4;

#define IMG_H 56
#define IMG_W 56
#define CIN 256
#define COUT 256
#define TH 8        // output rows per block
#define TW 16       // output cols per block
#define XR 10       // halo rows
#define XCOL 18     // halo cols
#define CK 32       // c-chunk
#define PH 58       // padded H (1-px zero border)
#define PW 58       // padded W
#define NPIX (XR * XCOL)            // 180 pixels per halo tile
#define NUNIT (NPIX * 5)            // 900 16B-units (5th = pad, skipped)
#define NISSUE ((NUNIT + 63) / 64)  // 15 wave-issues
#define XS_ELEMS (NPIX * 40)        // 7200 bf16 per buffer (80B/pixel)

#define XBF_BYTES ((size_t)32 * PH * PW * CIN * 2)   // 55,115,776
#define WT_BYTES  ((size_t)9 * COUT * CIN * 2)       // 1,179,648

// ---- weight permute: W[k][c][3][3] fp32 -> wt2 in MFMA fragment order ------
// elem offset = t*65536 + ch*8192 + half*4096 + fn*512 + lane*8 + j
// maps to W[k][c] tap t with k=half*128+fn*16+(lane&15), c=ch*32+(lane>>4)*8+j
__global__ void wt_permute(const float* __restrict__ W, bf16_t* __restrict__ wt2) {
    int u = blockIdx.x * 256 + threadIdx.x;   // 73728 groups
    int lane = u & 63;
    int fn   = (u >> 6) & 7;
    int half = (u >> 9) & 1;
    int ch   = (u >> 10) & 7;
    int t    = u >> 13;
    int g = lane >> 4, pc = lane & 15;
    int k  = half * 128 + fn * 16 + pc;
    int cb = ch * 32 + g * 8;
    bf16x8 v;
    #pragma unroll
    for (int j = 0; j < 8; ++j)
        v[j] = (bf16_t)W[(k * CIN + cb + j) * 9 + t];
    *(bf16x8*)(wt2 + (size_t)u * 8) = v;
}

// ---- x transpose: x[n][c][h][w] fp32 -> xbf[n][ph][pw][c] bf16, borders=0 ---
#define LSP 258   // LDS row stride (elems)
__global__ __launch_bounds__(256)
void x_to_bf16(const float* __restrict__ x, bf16_t* __restrict__ xbf) {
    __shared__ bf16_t ls[IMG_W * LSP];
    const int n = blockIdx.y, ph = blockIdx.x;   // ph: 0..57 padded row
    bf16_t* drow = xbf + (size_t)(n * PH + ph) * PW * CIN;
    const f32x4 zf = {0.f, 0.f, 0.f, 0.f};
    if (ph == 0 || ph == PH - 1) {
        for (int i = threadIdx.x; i < PW * CIN / 8; i += 256)
            ((f32x4*)drow)[i] = zf;          // zero whole padded row
        return;
    }
    // zero left (w=0) and right (w=57) border pixels
    for (int i = threadIdx.x; i < 2 * CIN / 8; i += 256) {
        int side = i >> 5, off = i & 31;
        ((f32x4*)(drow + (side ? (size_t)(PW - 1) * CIN : 0)))[off] = zf;
    }
    const int h = ph - 1;
    const float* src = x + ((size_t)n * CIN * IMG_H + h) * IMG_W;
    for (int e = threadIdx.x; e < CIN * IMG_W; e += 256) {
        int c = e / IMG_W, w = e - c * IMG_W;
        ls[w * LSP + c] = (bf16_t)src[(size_t)c * (IMG_H * IMG_W) + w];
    }
    __syncthreads();
    bf16_t* dst = drow + CIN;    // w=1 (first interior col)
    for (int i = threadIdx.x; i < IMG_W * (CIN / 8); i += 256) {
        int w = i >> 5, cp = (i & 31) * 8;
        bf16x8 v;
        #pragma unroll
        for (int j = 0; j < 8; ++j) v[j] = ls[w * LSP + cp + j];
        *(bf16x8*)(dst + (size_t)w * CIN + cp) = v;
    }
}

// ---- main conv: implicit GEMM; wave = 128 px x 64 k; A row-reuse over dh ----
__global__ __launch_bounds__(256, 2)
void conv_mfma(const bf16_t* __restrict__ xbf, const bf16_t* __restrict__ wt2,
               float* __restrict__ out) {
    __shared__ __align__(16) bf16_t xs[2][XS_ELEMS];   // 2 x 14400 B

    const int tid  = threadIdx.x;
    const int lane = tid & 63;
    const int kq   = tid >> 6;      // wave k-quarter (0..3)
    const int n    = blockIdx.z;
    const int h0   = blockIdx.y * TH;
    const int w0   = blockIdx.x * TW;

    const int pc = lane & 15;
    const int g  = lane >> 4;

    f32x4 acc[8][4] = {};           // 128 pixels x 64 channels per wave
    // B fragment base: half=kq>>1, fn=(kq&1)*4+q
    const bf16_t* wfrag = wt2 + (size_t)lane * 8 + (size_t)(kq >> 1) * 4096
                              + (size_t)(kq & 1) * 2048;
    const bf16_t* xn = xbf + (size_t)n * (PH * PW * CIN);

    // staging descriptors as 32-bit element offsets (-1 = inactive slot)
    int soff[4];
    #pragma unroll
    for (int s = 0; s < 4; ++s) {
        int j = kq + s * 4;
        int u = j * 64 + lane;
        int p = u / 5, q = u - p * 5;
        bool ok = (j < NISSUE) && (u < NUNIT) && (q < 4);
        int r = p / XCOL, col = p - r * XCOL;
        int w = w0 + col; if (w > PW - 1) w = PW - 1;   // clamp into zero border
        int rr = (r > XR - 1) ? (XR - 1) : r;
        soff[s] = ok ? (((h0 + rr) * PW + w) * CIN + q * 8) : -1;
    }

    auto STAGE = [&](int buf, int ch) {
        #pragma unroll
        for (int s = 0; s < 4; ++s)
            if (soff[s] >= 0)
                __builtin_amdgcn_global_load_lds(
                    (const __attribute__((address_space(1))) void*)(xn + soff[s] + ch * CK),
                    (__attribute__((address_space(3))) void*)(&xs[buf][(kq + s * 4) * 512]),
                    16, 0, 0);
    };

    STAGE(0, 0);
    __syncthreads();   // buf0 ready

    for (int ch = 0; ch < 8; ++ch) {
        const int cur = ch & 1;
        const bf16_t* wch = wfrag + (size_t)ch * 8192;

        // first tap (t=0) B loads before STAGE (keep their wait ahead in vmcnt FIFO)
        bf16x8 bcur[4], bnext[4];
        #pragma unroll
        for (int q = 0; q < 4; ++q)
            bcur[q] = *(const bf16x8*)(wch + q * 512);

        if (ch < 7) STAGE(cur ^ 1, ch + 1);   // async prefetch next chunk

        // tap order: dw outer, dh inner (t = dh*3+dw); A rows loaded once per dw
        #pragma unroll
        for (int dw = 0; dw < 3; ++dw) {
            bf16x8 a[10];
            #pragma unroll
            for (int r = 0; r < 10; ++r)
                a[r] = *(const bf16x8*)&xs[cur][(r * XCOL + pc + dw) * 40 + g * 8];
            #pragma unroll
            for (int dh = 0; dh < 3; ++dh) {
                // prefetch next tap's B fragments (reg dbuf)
                const bool last = (dw == 2) && (dh == 2);
                if (!last) {
                    const int tn = (dh < 2) ? ((dh + 1) * 3 + dw) : (dw + 1);
                    const bf16_t* wp = wch + (size_t)tn * 65536;
                    #pragma unroll
                    for (int q = 0; q < 4; ++q)
                        bnext[q] = *(const bf16x8*)(wp + q * 512);
                }
                #pragma unroll
                for (int fm = 0; fm < 8; ++fm)
                    #pragma unroll
                    for (int q = 0; q < 4; ++q)
                        acc[fm][q] = __builtin_amdgcn_mfma_f32_16x16x32_bf16(
                            a[fm + dh], bcur[q], acc[fm][q], 0, 0, 0);
                if (!last) {
                    #pragma unroll
                    for (int q = 0; q < 4; ++q) bcur[q] = bnext[q];  // SSA rename
                }
            }
        }
        __syncthreads();   // xs[cur] free; next buffer's loads drained
    }

    // epilogue: C/D col=lane&15 (within-16 k), row=g*4+reg (w offset)
    const int wcol = w0 + g * 4;
    if (wcol < IMG_W) {
        #pragma unroll
        for (int fm = 0; fm < 8; ++fm) {
            int hh = h0 + fm;
            #pragma unroll
            for (int q = 0; q < 4; ++q) {
                int k = kq * 64 + q * 16 + pc;
                *(f32x4*)&out[((n * COUT + k) * IMG_H + hh) * IMG_W + wcol] = acc[fm][q];
            }
        }
    }
}

// ---- mid fallback: B direct global, scalar x staging (round-2 proven) -------
#define CPAD 40
__global__ __launch_bounds__(256, 2)
void conv_mfma_v2(const float* __restrict__ x, const bf16_t* __restrict__ wt2,
                  float* __restrict__ out) {
    __shared__ bf16_t xsl[XR * XCOL * CPAD];
    const int tid  = threadIdx.x;
    const int lane = tid & 63;
    const int wid  = tid >> 6;
    const int n    = blockIdx.z;
    const int h0   = blockIdx.y * TH;
    const int w0   = blockIdx.x * TW;
    const int wm   = wid >> 1;
    const int half = wid & 1;
    const int pc = lane & 15;
    const int g  = lane >> 4;
    const int c0 = g * 8;
    f32x4 acc[4][8] = {};
    const bf16_t* wch_base = wt2 + (size_t)lane * 8 + (size_t)half * 4096;
    for (int ch = 0; ch < 8; ++ch) {
        __syncthreads();
        for (int e = tid; e < XR * XCOL * CK; e += 256) {
            int col = e % XCOL;
            int r   = (e / XCOL) % XR;
            int ci  = e / (XCOL * XR);
            int hh = h0 - 1 + r;
            int ww = w0 - 1 + col;
            float v = 0.f;
            if ((unsigned)hh < (unsigned)IMG_H && (unsigned)ww < (unsigned)IMG_W)
                v = x[((n * CIN + ch * CK + ci) * IMG_H + hh) * IMG_W + ww];
            xsl[(r * XCOL + col) * CPAD + ci] = (bf16_t)v;
        }
        __syncthreads();
        const bf16_t* wch = wch_base + (size_t)ch * 8192;
        #pragma unroll 3
        for (int t = 0; t < 9; ++t) {
            const int dh = t / 3, dw = t % 3;
            const bf16_t* wp = wch + (size_t)t * 65536;
            bf16x8 b[8];
            #pragma unroll
            for (int fn = 0; fn < 8; ++fn)
                b[fn] = *(const bf16x8*)(wp + fn * 512);
            bf16x8 a[4];
            #pragma unroll
            for (int fm = 0; fm < 4; ++fm)
                a[fm] = *(const bf16x8*)&xsl[((wm * 4 + fm + dh) * XCOL + (pc + dw)) * CPAD + c0];
            #pragma unroll
            for (int fm = 0; fm < 4; ++fm)
                #pragma unroll
                for (int fn = 0; fn < 8; ++fn)
                    acc[fm][fn] = __builtin_amdgcn_mfma_f32_16x16x32_bf16(
                        a[fm], b[fn], acc[fm][fn], 0, 0, 0);
        }
    }
    const int wcol = w0 + g * 4;
    if (wcol < IMG_W) {
        #pragma unroll
        for (int fm = 0; fm < 4; ++fm) {
            int hh = h0 + wm * 4 + fm;
            #pragma unroll
            for (int fn = 0; fn < 8; ++fn) {
                int k = half * 128 + fn * 16 + pc;
                *(f32x4*)&out[((n * COUT + k) * IMG_H + hh) * IMG_W + wcol] = acc[fm][fn];
            }
        }
    }
}

// ---- last-resort fallback: naive fp32 conv ----------------------------------
__global__ void conv_naive(const float* __restrict__ x, const float* __restrict__ W,
                           float* __restrict__ out, int total) {
    int i = blockIdx.x * 256 + threadIdx.x;
    if (i >= total) return;
    int w = i % IMG_W;
    int h = (i / IMG_W) % IMG_H;
    int k = (i / (IMG_W * IMG_H)) % COUT;
    int n = i / (IMG_W * IMG_H * COUT);
    float s = 0.f;
    for (int c = 0; c < CIN; ++c) {
        #pragma unroll
        for (int dh = 0; dh < 3; ++dh) {
            int hh = h + dh - 1;
            if ((unsigned)hh >= (unsigned)IMG_H) continue;
            #pragma unroll
            for (int dw = 0; dw < 3; ++dw) {
                int ww = w + dw - 1;
                if ((unsigned)ww >= (unsigned)IMG_W) continue;
                s += x[((n * CIN + c) * IMG_H + hh) * IMG_W + ww] *
                     W[((k * CIN + c) * 3 + dh) * 3 + dw];
            }
        }
    }
    out[i] = s;
}

extern "C" void kernel_launch(void* const* d_in, const int* in_sizes, int n_in,
                              void* d_out, int out_size, void* d_ws, size_t ws_size,
                              hipStream_t stream) {
    const float* x = (const float*)d_in[0];
    const float* W = (const float*)d_in[1];
    float* out = (float*)d_out;

    if (ws_size >= XBF_BYTES + WT_BYTES) {
        bf16_t* xbf = (bf16_t*)d_ws;
        bf16_t* wt2 = (bf16_t*)((char*)d_ws + XBF_BYTES);
        wt_permute<<<dim3(288), dim3(256), 0, stream>>>(W, wt2);
        x_to_bf16<<<dim3(PH, 32), dim3(256), 0, stream>>>(x, xbf);   // writes borders
        conv_mfma<<<dim3(4, 7, 32), dim3(256), 0, stream>>>(xbf, wt2, out);
    } else if (ws_size >= WT_BYTES) {
        bf16_t* wt2 = (bf16_t*)d_ws;
        wt_permute<<<dim3(288), dim3(256), 0, stream>>>(W, wt2);
        conv_mfma_v2<<<dim3(4, 7, 32), dim3(256), 0, stream>>>(x, wt2, out);
    } else {
        int total = 32 * COUT * IMG_H * IMG_W;
        conv_naive<<<dim3((total + 255) / 256), dim3(256), 0, stream>>>(x, W, out, total);
    }
}

// Round 8
// 156.192 us; speedup vs baseline: 2.2095x; 1.0257x over previous
//
#include <hip/hip_runtime.h>

typedef __bf16 bf16_t;
typedef __attribute__((ext_vector_type(8))) __bf16 bf16x8;
typedef __attribute__((ext_vector_type(4))) float f32x4;

#define IMG_H 56
#define IMG_W 56
#define CIN 256
#define COUT 256
#define TH 8        // output rows per block
#define TW 16       // output cols per block
#define XR 10       // halo rows
#define XCOL 18     // halo cols
#define CK 32       // c-chunk
#define PH 58       // padded H (1-px zero border)
#define PW 58       // padded W
#define NPIX (XR * XCOL)            // 180 pixels per halo tile
#define NUNIT (NPIX * 5)            // 900 16B-units (5th = pad, skipped)
#define NISSUE ((NUNIT + 63) / 64)  // 15 wave-issues
#define XS_ELEMS (NPIX * 40)        // 7200 bf16 per buffer (80B/pixel)

#define XBF_BYTES ((size_t)32 * PH * PW * CIN * 2)   // 55,115,776
#define WT_BYTES  ((size_t)9 * COUT * CIN * 2)       // 1,179,648

// ---- weight permute: W[k][c][3][3] fp32 -> wt2 in MFMA fragment order ------
// elem offset = t*65536 + ch*8192 + half*4096 + fn*512 + lane*8 + j
// maps to W[k][c] tap t with k=half*128+fn*16+(lane&15), c=ch*32+(lane>>4)*8+j
__global__ void wt_permute(const float* __restrict__ W, bf16_t* __restrict__ wt2) {
    int u = blockIdx.x * 256 + threadIdx.x;   // 73728 groups
    int lane = u & 63;
    int fn   = (u >> 6) & 7;
    int half = (u >> 9) & 1;
    int ch   = (u >> 10) & 7;
    int t    = u >> 13;
    int g = lane >> 4, pc = lane & 15;
    int k  = half * 128 + fn * 16 + pc;
    int cb = ch * 32 + g * 8;
    bf16x8 v;
    #pragma unroll
    for (int j = 0; j < 8; ++j)
        v[j] = (bf16_t)W[(k * CIN + cb + j) * 9 + t];
    *(bf16x8*)(wt2 + (size_t)u * 8) = v;
}

// ---- x transpose: x[n][c][h][w] fp32 -> xbf[n][ph][pw][c] bf16, borders=0 ---
#define LSP 258   // LDS row stride (elems)
__global__ __launch_bounds__(256)
void x_to_bf16(const float* __restrict__ x, bf16_t* __restrict__ xbf) {
    __shared__ bf16_t ls[IMG_W * LSP];
    const int n = blockIdx.y, ph = blockIdx.x;   // ph: 0..57 padded row
    bf16_t* drow = xbf + (size_t)(n * PH + ph) * PW * CIN;
    const f32x4 zf = {0.f, 0.f, 0.f, 0.f};
    if (ph == 0 || ph == PH - 1) {
        for (int i = threadIdx.x; i < PW * CIN / 8; i += 256)
            ((f32x4*)drow)[i] = zf;          // zero whole padded row
        return;
    }
    // zero left (w=0) and right (w=57) border pixels
    for (int i = threadIdx.x; i < 2 * CIN / 8; i += 256) {
        int side = i >> 5, off = i & 31;
        ((f32x4*)(drow + (side ? (size_t)(PW - 1) * CIN : 0)))[off] = zf;
    }
    const int h = ph - 1;
    const float* src = x + ((size_t)n * CIN * IMG_H + h) * IMG_W;
    for (int e = threadIdx.x; e < CIN * IMG_W; e += 256) {
        int c = e / IMG_W, w = e - c * IMG_W;
        ls[w * LSP + c] = (bf16_t)src[(size_t)c * (IMG_H * IMG_W) + w];
    }
    __syncthreads();
    bf16_t* dst = drow + CIN;    // w=1 (first interior col)
    for (int i = threadIdx.x; i < IMG_W * (CIN / 8); i += 256) {
        int w = i >> 5, cp = (i & 31) * 8;
        bf16x8 v;
        #pragma unroll
        for (int j = 0; j < 8; ++j) v[j] = ls[w * LSP + cp + j];
        *(bf16x8*)(dst + (size_t)w * CIN + cp) = v;
    }
}

// ---- main conv: implicit GEMM; wave = 64 px x 64 k (FM=4, FN=4);
//      block = 128 px x 128 k; 3 blocks/CU for latency overlap ---------------
__global__ __launch_bounds__(256, 3)
void conv_mfma(const bf16_t* __restrict__ xbf, const bf16_t* __restrict__ wt2,
               float* __restrict__ out) {
    __shared__ __align__(16) bf16_t xs[2][XS_ELEMS];   // 2 x 14400 B

    const int tid  = threadIdx.x;
    const int lane = tid & 63;
    const int wid  = tid >> 6;      // 0..3
    const int n    = blockIdx.z >> 1;
    const int bk   = blockIdx.z & 1;    // k-half of this block
    const int h0   = blockIdx.y * TH;
    const int w0   = blockIdx.x * TW;

    const int wm   = wid >> 1;      // px half (rows wm*4 .. wm*4+3 of 16px frags)
    const int kq2  = wid & 1;       // k quarter-within-half
    const int pc   = lane & 15;
    const int g    = lane >> 4;

    f32x4 acc[4][4] = {};           // 64 px x 64 k per wave
    // B fragment base: k = bk*128 + kq2*64 + q*16 + pc  (half=bk, fn=kq2*4+q)
    const bf16_t* wfrag = wt2 + (size_t)lane * 8 + (size_t)bk * 4096
                              + (size_t)kq2 * 2048;
    const bf16_t* xn = xbf + (size_t)n * (PH * PW * CIN);

    // staging descriptors as 32-bit element offsets (-1 = inactive slot)
    int soff[4];
    #pragma unroll
    for (int s = 0; s < 4; ++s) {
        int j = wid + s * 4;
        int u = j * 64 + lane;
        int p = u / 5, q = u - p * 5;
        bool ok = (j < NISSUE) && (u < NUNIT) && (q < 4);
        int r = p / XCOL, col = p - r * XCOL;
        int w = w0 + col; if (w > PW - 1) w = PW - 1;   // clamp into zero border
        int rr = (r > XR - 1) ? (XR - 1) : r;
        soff[s] = ok ? (((h0 + rr) * PW + w) * CIN + q * 8) : -1;
    }

    auto STAGE = [&](int buf, int ch) {
        #pragma unroll
        for (int s = 0; s < 4; ++s)
            if (soff[s] >= 0)
                __builtin_amdgcn_global_load_lds(
                    (const __attribute__((address_space(1))) void*)(xn + soff[s] + ch * CK),
                    (__attribute__((address_space(3))) void*)(&xs[buf][(wid + s * 4) * 512]),
                    16, 0, 0);
    };

    STAGE(0, 0);
    __syncthreads();   // buf0 ready

    for (int ch = 0; ch < 8; ++ch) {
        const int cur = ch & 1;
        const bf16_t* wch = wfrag + (size_t)ch * 8192;

        // first tap (t=0) B loads before STAGE (their wait ahead in vmcnt FIFO)
        bf16x8 bcur[4], bnext[4];
        #pragma unroll
        for (int q = 0; q < 4; ++q)
            bcur[q] = *(const bf16x8*)(wch + q * 512);

        if (ch < 7) STAGE(cur ^ 1, ch + 1);   // async prefetch next chunk

        // tap order: dw outer, dh inner (t = dh*3+dw); A rows loaded once per dw
        #pragma unroll
        for (int dw = 0; dw < 3; ++dw) {
            bf16x8 a[6];
            #pragma unroll
            for (int r = 0; r < 6; ++r)
                a[r] = *(const bf16x8*)&xs[cur][((wm * 4 + r) * XCOL + pc + dw) * 40 + g * 8];
            #pragma unroll
            for (int dh = 0; dh < 3; ++dh) {
                const bool last = (dw == 2) && (dh == 2);
                if (!last) {   // prefetch next tap's B fragments (reg dbuf)
                    const int tn = (dh < 2) ? ((dh + 1) * 3 + dw) : (dw + 1);
                    const bf16_t* wp = wch + (size_t)tn * 65536;
                    #pragma unroll
                    for (int q = 0; q < 4; ++q)
                        bnext[q] = *(const bf16x8*)(wp + q * 512);
                }
                #pragma unroll
                for (int fm = 0; fm < 4; ++fm)
                    #pragma unroll
                    for (int q = 0; q < 4; ++q)
                        acc[fm][q] = __builtin_amdgcn_mfma_f32_16x16x32_bf16(
                            a[fm + dh], bcur[q], acc[fm][q], 0, 0, 0);
                if (!last) {
                    #pragma unroll
                    for (int q = 0; q < 4; ++q) bcur[q] = bnext[q];  // SSA rename
                }
            }
        }
        __syncthreads();   // xs[cur] free; next buffer's loads drained
    }

    // epilogue: C/D col=lane&15 (within-16 k), row=g*4+reg (w offset)
    const int wcol = w0 + g * 4;
    if (wcol < IMG_W) {
        #pragma unroll
        for (int fm = 0; fm < 4; ++fm) {
            int hh = h0 + wm * 4 + fm;
            #pragma unroll
            for (int q = 0; q < 4; ++q) {
                int k = bk * 128 + kq2 * 64 + q * 16 + pc;
                *(f32x4*)&out[((n * COUT + k) * IMG_H + hh) * IMG_W + wcol] = acc[fm][q];
            }
        }
    }
}

// ---- mid fallback: B direct global, scalar x staging (round-2 proven) -------
#define CPAD 40
__global__ __launch_bounds__(256, 2)
void conv_mfma_v2(const float* __restrict__ x, const bf16_t* __restrict__ wt2,
                  float* __restrict__ out) {
    __shared__ bf16_t xsl[XR * XCOL * CPAD];
    const int tid  = threadIdx.x;
    const int lane = tid & 63;
    const int wid  = tid >> 6;
    const int n    = blockIdx.z;
    const int h0   = blockIdx.y * TH;
    const int w0   = blockIdx.x * TW;
    const int wm   = wid >> 1;
    const int half = wid & 1;
    const int pc = lane & 15;
    const int g  = lane >> 4;
    const int c0 = g * 8;
    f32x4 acc[4][8] = {};
    const bf16_t* wch_base = wt2 + (size_t)lane * 8 + (size_t)half * 4096;
    for (int ch = 0; ch < 8; ++ch) {
        __syncthreads();
        for (int e = tid; e < XR * XCOL * CK; e += 256) {
            int col = e % XCOL;
            int r   = (e / XCOL) % XR;
            int ci  = e / (XCOL * XR);
            int hh = h0 - 1 + r;
            int ww = w0 - 1 + col;
            float v = 0.f;
            if ((unsigned)hh < (unsigned)IMG_H && (unsigned)ww < (unsigned)IMG_W)
                v = x[((n * CIN + ch * CK + ci) * IMG_H + hh) * IMG_W + ww];
            xsl[(r * XCOL + col) * CPAD + ci] = (bf16_t)v;
        }
        __syncthreads();
        const bf16_t* wch = wch_base + (size_t)ch * 8192;
        #pragma unroll 3
        for (int t = 0; t < 9; ++t) {
            const int dh = t / 3, dw = t % 3;
            const bf16_t* wp = wch + (size_t)t * 65536;
            bf16x8 b[8];
            #pragma unroll
            for (int fn = 0; fn < 8; ++fn)
                b[fn] = *(const bf16x8*)(wp + fn * 512);
            bf16x8 a[4];
            #pragma unroll
            for (int fm = 0; fm < 4; ++fm)
                a[fm] = *(const bf16x8*)&xsl[((wm * 4 + fm + dh) * XCOL + (pc + dw)) * CPAD + c0];
            #pragma unroll
            for (int fm = 0; fm < 4; ++fm)
                #pragma unroll
                for (int fn = 0; fn < 8; ++fn)
                    acc[fm][fn] = __builtin_amdgcn_mfma_f32_16x16x32_bf16(
                        a[fm], b[fn], acc[fm][fn], 0, 0, 0);
        }
    }
    const int wcol = w0 + g * 4;
    if (wcol < IMG_W) {
        #pragma unroll
        for (int fm = 0; fm < 4; ++fm) {
            int hh = h0 + wm * 4 + fm;
            #pragma unroll
            for (int fn = 0; fn < 8; ++fn) {
                int k = half * 128 + fn * 16 + pc;
                *(f32x4*)&out[((n * COUT + k) * IMG_H + hh) * IMG_W + wcol] = acc[fm][fn];
            }
        }
    }
}

// ---- last-resort fallback: naive fp32 conv ----------------------------------
__global__ void conv_naive(const float* __restrict__ x, const float* __restrict__ W,
                           float* __restrict__ out, int total) {
    int i = blockIdx.x * 256 + threadIdx.x;
    if (i >= total) return;
    int w = i % IMG_W;
    int h = (i / IMG_W) % IMG_H;
    int k = (i / (IMG_W * IMG_H)) % COUT;
    int n = i / (IMG_W * IMG_H * COUT);
    float s = 0.f;
    for (int c = 0; c < CIN; ++c) {
        #pragma unroll
        for (int dh = 0; dh < 3; ++dh) {
            int hh = h + dh - 1;
            if ((unsigned)hh >= (unsigned)IMG_H) continue;
            #pragma unroll
            for (int dw = 0; dw < 3; ++dw) {
                int ww = w + dw - 1;
                if ((unsigned)ww >= (unsigned)IMG_W) continue;
                s += x[((n * CIN + c) * IMG_H + hh) * IMG_W + ww] *
                     W[((k * CIN + c) * 3 + dh) * 3 + dw];
            }
        }
    }
    out[i] = s;
}

extern "C" void kernel_launch(void* const* d_in, const int* in_sizes, int n_in,
                              void* d_out, int out_size, void* d_ws, size_t ws_size,
                              hipStream_t stream) {
    const float* x = (const float*)d_in[0];
    const float* W = (const float*)d_in[1];
    float* out = (float*)d_out;

    if (ws_size >= XBF_BYTES + WT_BYTES) {
        bf16_t* xbf = (bf16_t*)d_ws;
        bf16_t* wt2 = (bf16_t*)((char*)d_ws + XBF_BYTES);
        wt_permute<<<dim3(288), dim3(256), 0, stream>>>(W, wt2);
        x_to_bf16<<<dim3(PH, 32), dim3(256), 0, stream>>>(x, xbf);   // writes borders
        conv_mfma<<<dim3(4, 7, 64), dim3(256), 0, stream>>>(xbf, wt2, out);
    } else if (ws_size >= WT_BYTES) {
        bf16_t* wt2 = (bf16_t*)d_ws;
        wt_permute<<<dim3(288), dim3(256), 0, stream>>>(W, wt2);
        conv_mfma_v2<<<dim3(4, 7, 32), dim3(256), 0, stream>>>(x, wt2, out);
    } else {
        int total = 32 * COUT * IMG_H * IMG_W;
        conv_naive<<<dim3((total + 255) / 256), dim3(256), 0, stream>>>(x, W, out, total);
    }
}